// Round 12
// baseline (717.678 us; speedup 1.0000x reference)
//
#include <hip/hip_runtime.h>
#include <hip/hip_bf16.h>
#include <math.h>

#define B_ 16
#define T_ 1024
#define P_ 48
#define S_ 12
#define A_ 24
#define D_ 768
#define D4_ 3072
#define G3_ 2304
#define RV_ (B_*T_)      // 16384
#define RP_ (B_*P_)      // 768
#define RA_ (B_*S_*A_)   // 4608
#define RH_ (B_*S_)      // 192
#define RPB_ 288

typedef float f32x4 __attribute__((ext_vector_type(4)));
typedef short s16x8 __attribute__((ext_vector_type(8)));

__device__ __forceinline__ unsigned short f2bf(float f) {
  unsigned int u = __float_as_uint(f);
  u += 0x7FFF + ((u >> 16) & 1);
  return (unsigned short)(u >> 16);
}
__device__ __forceinline__ unsigned int pk2(float lo, float hi) {
  return (unsigned int)f2bf(lo) | ((unsigned int)f2bf(hi) << 16);
}
__device__ __forceinline__ float bf2f(unsigned short u) {
  return __uint_as_float(((unsigned int)u) << 16);
}
__device__ __forceinline__ void gload16(const void* g, void* l) {
  __builtin_amdgcn_global_load_lds((const __attribute__((address_space(1))) void*)g,
                                   (__attribute__((address_space(3))) void*)l, 16, 0, 0);
}
__device__ __forceinline__ int xcd_swizzle(int orig, int nwg) {
  int q = nwg >> 3, r = nwg & 7;
  int xcd = orig & 7, local = orig >> 3;
  return (xcd < r ? xcd * (q + 1) : r * (q + 1) + (xcd - r) * q) + local;
}

#define VMW8 asm volatile("s_waitcnt vmcnt(8)" ::: "memory")
#define VMW4 asm volatile("s_waitcnt vmcnt(4)" ::: "memory")
#define VMW0 asm volatile("s_waitcnt vmcnt(0)" ::: "memory")

// ============ gemm256m: r3-proven 256x256 BK=64 dbuf GEMM (78us/557TF on wp1_bot) ============
// One barrier per K-tile, 8 waves, 128KB LDS. Extended with: M-guards, per-row-block
// weight select (wsplit), and fused epilogues.
// MODE: 0 = bf16 -> C0 (B2D optional)
//       2 = mlp-L2 routing: tiles bm0<16384 -> atomic wseg-weighted vseg;
//           rows<20992 -> QAB col+768 (bf16); else -> Tout f32
template<int ACT, int MODE, int B2D>
__global__ __launch_bounds__(512, 2)
void gemm256m(const unsigned short* __restrict__ A,
              const unsigned short* __restrict__ Wt0, const float* __restrict__ bias0,
              const unsigned short* __restrict__ Wt1, const float* __restrict__ bias1,
              int wsplit,
              void* __restrict__ C0, int ldc0,
              const float* __restrict__ xv0,   // MODE2: wseg
              float* __restrict__ xv1,         // MODE2: vseg
              unsigned short* __restrict__ xq, // MODE2: QAB
              float* __restrict__ xt,          // MODE2: Tout
              int M, int N, int K)
{
  __shared__ __align__(16) unsigned short As[2][16384];  // [buf][256 rows][64 k]
  __shared__ __align__(16) unsigned short Bs[2][16384];
  const int tid  = threadIdx.x;
  const int lane = tid & 63;
  const int wid  = tid >> 6;                 // 0..7
  const int wm = (wid >> 2) * 128;           // 2 waves along M
  const int wn = (wid & 3) * 64;             // 4 waves along N
  const int gx = gridDim.x;
  int swz = xcd_swizzle(blockIdx.y * gx + blockIdx.x, gx * gridDim.y);
  const int bm0 = (swz / gx) * 256, bn0 = (swz % gx) * 256;

  const unsigned short* W = (bm0 < wsplit) ? Wt0 : Wt1;
  const float* bias = (bm0 < wsplit) ? bias0 : bias1;

  const int srow = wid * 32 + (lane >> 3);
  const int skk  = (lane & 7) * 8;
  const unsigned short* gA[4];
  const unsigned short* gB[4];
#pragma unroll
  for (int c = 0; c < 4; ++c) {
    int r = bm0 + srow + c * 8; if (r > M - 1) r = M - 1;
    gA[c] = A + (size_t)r * K + skk;
    gB[c] = W + (size_t)(bn0 + srow + c * 8) * K + skk;
  }

  f32x4 acc[8][4] = {};
  const int fr = lane & 15, fq = lane >> 4;
  const int nt = K / 64;

#pragma unroll
  for (int c = 0; c < 4; ++c) {
    gload16(gA[c], &As[0][wid * 2048 + c * 512]);
    gload16(gB[c], &Bs[0][wid * 2048 + c * 512]);
  }
  __syncthreads();

  for (int t = 0; t < nt; ++t) {
    if (t + 1 < nt) {
      const int nb = (t + 1) & 1;
      const size_t ko = (size_t)(t + 1) * 64;
#pragma unroll
      for (int c = 0; c < 4; ++c) {
        gload16(gA[c] + ko, &As[nb][wid * 2048 + c * 512]);
        gload16(gB[c] + ko, &Bs[nb][wid * 2048 + c * 512]);
      }
    }
    const int cb = t & 1;
#pragma unroll
    for (int ks = 0; ks < 2; ++ks) {
      s16x8 af[8], bf4[4];
#pragma unroll
      for (int i = 0; i < 8; ++i)
        af[i] = *(const s16x8*)(&As[cb][(wm + i * 16 + fr) * 64 + ks * 32 + fq * 8]);
#pragma unroll
      for (int i = 0; i < 4; ++i)
        bf4[i] = *(const s16x8*)(&Bs[cb][(wn + i * 16 + fr) * 64 + ks * 32 + fq * 8]);
#pragma unroll
      for (int mi = 0; mi < 8; ++mi)
#pragma unroll
        for (int ni = 0; ni < 4; ++ni)
          acc[mi][ni] = __builtin_amdgcn_mfma_f32_16x16x32_bf16(af[mi], bf4[ni], acc[mi][ni], 0, 0, 0);
    }
    __syncthreads();   // drains vmcnt (next tile staged) + cur-buf reads done
  }

  // ---------------- epilogue ----------------
  if (MODE == 2 && bm0 < 16384) {
    // video rows: vseg[b,col] += sum_rows wseg[row]*(acc+bias)  (video_v never stored)
    float s[4] = {0.f, 0.f, 0.f, 0.f};
#pragma unroll
    for (int mi = 0; mi < 8; ++mi)
#pragma unroll
      for (int r = 0; r < 4; ++r) {
        int row = bm0 + wm + mi * 16 + fq * 4 + r;
        float wv = xv0[row];
#pragma unroll
        for (int ni = 0; ni < 4; ++ni) {
          int col = bn0 + wn + ni * 16 + fr;
          s[ni] += wv * (acc[mi][ni][r] + bias[col]);
        }
      }
    int b = bm0 >> 10;
#pragma unroll
    for (int ni = 0; ni < 4; ++ni) {
      s[ni] += __shfl_xor(s[ni], 16);
      s[ni] += __shfl_xor(s[ni], 32);
      if (fq == 0) atomicAdd(&xv1[b * D_ + bn0 + wn + ni * 16 + fr], s[ni]);
    }
  } else {
#pragma unroll
    for (int ni = 0; ni < 4; ++ni) {
      int col = bn0 + wn + ni * 16 + fr;
      float bb = B2D ? 0.f : bias[col];
#pragma unroll
      for (int mi = 0; mi < 8; ++mi)
#pragma unroll
        for (int r = 0; r < 4; ++r) {
          int row = bm0 + wm + mi * 16 + fq * 4 + r;
          if (row >= M) continue;
          float v = acc[mi][ni][r] + (B2D ? bias[(size_t)(row / RPB_) * N + col] : bb);
          if (ACT) v = fmaxf(v, 0.f);
          if (MODE == 2) {
            if (row < 20992) xq[(size_t)(row - 16384) * 1536 + D_ + col] = f2bf(v);
            else             xt[(size_t)(row - 20992) * D_ + col] = v;
          } else {
            ((unsigned short*)C0)[(size_t)row * ldc0 + col] = f2bf(v);
          }
        }
    }
  }
}

// ====================== gemmph128: counted-vmcnt phased GEMM (kept for steps 9/11/13) ======
// MODE: 0 = bf16 out (optional row-split C0/C1 at osplit)
//       3 = fused logits: atomicAdd(logits[row], sum_col relu(v)*wq2[col])
template<int ACT, int MODE>
__global__ __launch_bounds__(256, 2)
void gemmph(const unsigned short* __restrict__ A,
            const unsigned short* __restrict__ Wt0, const float* __restrict__ bias0,
            const unsigned short* __restrict__ Wt1, const float* __restrict__ bias1,
            int wsplit,
            void* __restrict__ C0, int ldc0,
            void* __restrict__ C1, int ldc1, int osplit,
            const float* __restrict__ xv0,   // MODE3: wq2
            float* __restrict__ xv1,         // MODE3: logits
            int M, int N, int K)
{
  __shared__ __align__(16) unsigned short As[2][2][128][32];
  __shared__ __align__(16) unsigned short Bs[2][2][128][32];
  const int tid  = threadIdx.x;
  const int lane = tid & 63;
  const int wid  = tid >> 6;
  const int wm = (wid >> 1) * 64;
  const int wn = (wid & 1) * 64;
  const int gx = gridDim.x;
  int swz = xcd_swizzle(blockIdx.y * gx + blockIdx.x, gx * gridDim.y);
  const int bm0 = (swz / gx) * 128, bn0 = (swz % gx) * 128;

  const unsigned short* W = (bm0 < wsplit) ? Wt0 : Wt1;
  const float* bias = (bm0 < wsplit) ? bias0 : bias1;

  const int srow = (wid * 2) * 16 + (lane >> 2);
  const int sslot = lane & 3;

  f32x4 acc[4][4] = {};
  const int fr = lane & 15, fq = lane >> 4;
  const int sws = (fq ^ (fr & 3)) * 8;

  auto stage = [&](int buf, int ks, int kt) {
#pragma unroll
    for (int c = 0; c < 2; ++c) {
      int r = srow + c * 16;
      int ksl = sslot ^ (r & 3);
      int ar = bm0 + r; if (ar > M - 1) ar = M - 1;
      gload16(A + (size_t)ar * K + kt * 64 + ks * 32 + ksl * 8, &As[buf][ks][(wid * 2 + c) * 16][0]);
      gload16(W + (size_t)(bn0 + r) * K + kt * 64 + ks * 32 + ksl * 8, &Bs[buf][ks][(wid * 2 + c) * 16][0]);
    }
  };

  auto compute = [&](int cb, int ks) {
    s16x8 af[4], bf4[4];
#pragma unroll
    for (int i = 0; i < 4; ++i)
      af[i] = *(const s16x8*)(&As[cb][ks][wm + i * 16 + fr][sws]);
#pragma unroll
    for (int i = 0; i < 4; ++i)
      bf4[i] = *(const s16x8*)(&Bs[cb][ks][wn + i * 16 + fr][sws]);
    __builtin_amdgcn_s_setprio(1);
#pragma unroll
    for (int mi = 0; mi < 4; ++mi)
#pragma unroll
      for (int ni = 0; ni < 4; ++ni)
        acc[mi][ni] = __builtin_amdgcn_mfma_f32_16x16x32_bf16(af[mi], bf4[ni], acc[mi][ni], 0, 0, 0);
    __builtin_amdgcn_s_setprio(0);
  };

  const int nt = K >> 6;
  stage(0, 0, 0); stage(0, 1, 0); stage(1, 0, 1);
  for (int t = 0; t < nt; ++t) {
    const int cb = t & 1;
    if (t + 1 < nt) { VMW8; __builtin_amdgcn_s_barrier(); stage(cb ^ 1, 1, t + 1); }
    else            { VMW4; __builtin_amdgcn_s_barrier(); }
    compute(cb, 0);
    if (t + 2 < nt)       { VMW8; __builtin_amdgcn_s_barrier(); stage(cb, 0, t + 2); }
    else if (t + 2 == nt) { VMW8; __builtin_amdgcn_s_barrier(); }
    else                  { VMW0; __builtin_amdgcn_s_barrier(); }
    compute(cb, 1);
  }

  if (MODE == 3) {
#pragma unroll
    for (int mi = 0; mi < 4; ++mi)
#pragma unroll
      for (int r = 0; r < 4; ++r) {
        int row = bm0 + wm + mi * 16 + fq * 4 + r;
        float part = 0.f;
#pragma unroll
        for (int ni = 0; ni < 4; ++ni) {
          int col = bn0 + wn + ni * 16 + fr;
          float v = fmaxf(acc[mi][ni][r] + bias[col], 0.f);
          part += v * xv0[col];
        }
        part += __shfl_xor(part, 1);
        part += __shfl_xor(part, 2);
        part += __shfl_xor(part, 4);
        part += __shfl_xor(part, 8);
        if (fr == 0 && row < M) atomicAdd(&xv1[row], part);
      }
  } else {
#pragma unroll
    for (int ni = 0; ni < 4; ++ni) {
      int col = bn0 + wn + ni * 16 + fr;
      float bb = bias[col];
#pragma unroll
      for (int mi = 0; mi < 4; ++mi)
#pragma unroll
        for (int r = 0; r < 4; ++r) {
          int row = bm0 + wm + mi * 16 + fq * 4 + r;
          if (row >= M) continue;
          float v = acc[mi][ni][r] + bb;
          if (ACT) v = fmaxf(v, 0.f);
          if (osplit && row >= osplit) ((unsigned short*)C1)[(size_t)(row - osplit) * ldc1 + col] = f2bf(v);
          else ((unsigned short*)C0)[(size_t)row * ldc0 + col] = f2bf(v);
        }
    }
  }
}

// ====================== gemmdb_f32 (tiny baseb GEMM) ======================
__global__ __launch_bounds__(256, 2)
void gemmdb_f32(const unsigned short* __restrict__ A,
                const unsigned short* __restrict__ Wt,
                const float* __restrict__ bias,
                float* __restrict__ C0, int ldc0,
                int M, int N, int K)
{
  __shared__ __align__(16) unsigned short As[2][8192];
  __shared__ __align__(16) unsigned short Bs[2][8192];
  const int tid  = threadIdx.x;
  const int lane = tid & 63;
  const int wid  = tid >> 6;
  const int wm = (wid >> 1) * 64, wn = (wid & 1) * 64;
  const int bm0 = blockIdx.y * 128, bn0 = blockIdx.x * 128;
  const int srow = wid * 32 + (lane >> 3);
  const int skk  = (lane & 7) * 8;
  const unsigned short* gA[4];
  const unsigned short* gB[4];
#pragma unroll
  for (int c = 0; c < 4; ++c) {
    int r = bm0 + srow + c * 8; if (r > M - 1) r = M - 1;
    gA[c] = A  + (size_t)r * K + skk;
    gB[c] = Wt + (size_t)(bn0 + srow + c * 8) * K + skk;
  }
  f32x4 acc[4][4] = {};
  const int fr = lane & 15, fq = lane >> 4;
  const int nt = K / 64;
#pragma unroll
  for (int c = 0; c < 4; ++c) {
    gload16(gA[c], &As[0][wid * 2048 + c * 512]);
    gload16(gB[c], &Bs[0][wid * 2048 + c * 512]);
  }
  __syncthreads();
  for (int t = 0; t < nt; ++t) {
    if (t + 1 < nt) {
      const int nb = (t + 1) & 1;
      const int ko = (t + 1) * 64;
#pragma unroll
      for (int c = 0; c < 4; ++c) {
        gload16(gA[c] + ko, &As[nb][wid * 2048 + c * 512]);
        gload16(gB[c] + ko, &Bs[nb][wid * 2048 + c * 512]);
      }
    }
    const int cb = t & 1;
#pragma unroll
    for (int ks = 0; ks < 2; ++ks) {
      s16x8 af[4], bf4[4];
#pragma unroll
      for (int i = 0; i < 4; ++i) {
        af[i]  = *(const s16x8*)(&As[cb][(wm + i * 16 + fr) * 64 + ks * 32 + fq * 8]);
        bf4[i] = *(const s16x8*)(&Bs[cb][(wn + i * 16 + fr) * 64 + ks * 32 + fq * 8]);
      }
#pragma unroll
      for (int mi = 0; mi < 4; ++mi)
#pragma unroll
        for (int ni = 0; ni < 4; ++ni)
          acc[mi][ni] = __builtin_amdgcn_mfma_f32_16x16x32_bf16(af[mi], bf4[ni], acc[mi][ni], 0, 0, 0);
    }
    __syncthreads();
  }
#pragma unroll
  for (int ni = 0; ni < 4; ++ni) {
    int col = bn0 + wn + ni * 16 + fr;
    float bb = bias[col];
#pragma unroll
    for (int mi = 0; mi < 4; ++mi)
#pragma unroll
      for (int r = 0; r < 4; ++r) {
        int row = bm0 + wm + mi * 16 + fq * 4 + r;
        if (row < M) C0[(size_t)row * ldc0 + col] = acc[mi][ni][r] + bb;
      }
  }
}

// ====================== transposes + softmax ======================
struct TPtrs { const float* s[10]; unsigned short* d[10]; };

__global__ void transpose_all_k(TPtrs p, const float* __restrict__ ps, float* __restrict__ score) {
  constexpr int KN[10][2] = {{768,768},{768,768},{768,768},{768,768},{768,768},
                             {1536,3072},{1536,3072},{3072,768},{768,2304},{768,2304}};
  constexpr int TC[10] = {576,576,576,576,576,4608,4608,2304,1728,1728};
  int bid = blockIdx.x;
  if (bid == 17856) {
    int lane = threadIdx.x & 63, g = threadIdx.x >> 6;
#pragma unroll
    for (int rep = 0; rep < 4; ++rep) {
      int b = rep * 4 + g;
      float v = (lane < P_) ? ps[b * P_ + lane] : -INFINITY;
      float m = v;
      for (int o = 32; o > 0; o >>= 1) m = fmaxf(m, __shfl_xor(m, o));
      float e = (lane < P_) ? __expf(v - m) : 0.f;
      float s = e;
      for (int o = 32; o > 0; o >>= 1) s += __shfl_xor(s, o);
      if (lane < P_) score[b * P_ + lane] = e / s;
    }
    return;
  }
  int j = 0, local = bid;
  while (local >= TC[j]) { local -= TC[j]; ++j; }
  const int K = KN[j][0], N = KN[j][1];
  const float* W = p.s[j];
  unsigned short* Wt = p.d[j];
  int tx = local % (N >> 5), ty = local / (N >> 5);
  __shared__ float t[32][33];
  int n0 = tx * 32, k0 = ty * 32;
  int c = threadIdx.x & 31, r8 = threadIdx.x >> 5;
#pragma unroll
  for (int i = 0; i < 4; ++i) {
    int r = r8 + i * 8;
    t[r][c] = W[(size_t)(k0 + r) * N + n0 + c];
  }
  __syncthreads();
#pragma unroll
  for (int i = 0; i < 4; ++i) {
    int r = r8 + i * 8;
    Wt[(size_t)(n0 + r) * K + k0 + c] = f2bf(t[c][r]);
  }
}

// ====================== pack inputs + segment weights + zero vseg ======================
__global__ void pack_segw_k(const float* __restrict__ video, const float* __restrict__ abut,
                            const float* __restrict__ para, const float* __restrict__ atex,
                            const float* __restrict__ quest,
                            unsigned short* __restrict__ Acat,
                            const float* __restrict__ score, const int* __restrict__ starts,
                            const int* __restrict__ ends, float* __restrict__ w,
                            float* __restrict__ vseg) {
  int blk = blockIdx.x;
  if (blk < 9894) {
    int idx = blk * 256 + threadIdx.x;
    int r = idx / 96, d8 = (idx % 96) * 8;
    const float* src;
    if (r < 16384)      src = video + (size_t)r * D_;
    else if (r < 20992) src = abut + (size_t)(r - 16384) * D_;
    else if (r < 21760) src = para + (size_t)(r - 20992) * D_;
    else if (r < 26368) src = atex + (size_t)(r - 21760) * D_;
    else                src = quest + (size_t)(r - 26368) * D_;
    float4 a = *(const float4*)(src + d8);
    float4 b = *(const float4*)(src + d8 + 4);
    uint4 pk; pk.x = pk2(a.x, a.y); pk.y = pk2(a.z, a.w); pk.z = pk2(b.x, b.y); pk.w = pk2(b.z, b.w);
    *(uint4*)(Acat + (size_t)r * D_ + d8) = pk;
  } else {
    int idx = (blk - 9894) * 256 + threadIdx.x;
    int b = idx >> 10, t = idx & 1023;
    float acc = 0.f;
    for (int p = 0; p < P_; ++p) {
      int s = starts[b * P_ + p], e = ends[b * P_ + p];
      float sc = score[b * P_ + p];
      if (s >= e) { if (t == s) acc += sc; }
      else if (t >= s && t < e) acc += sc / (float)(e - s);
    }
    w[idx] = acc;
    if (idx < B_ * D_) vseg[idx] = 0.f;
  }
}

// ====================== tseg reduction over Tout para rows ======================
__global__ void tseg_k(const float* __restrict__ Tout, const float* __restrict__ score,
                       float* __restrict__ tseg) {
  int i = blockIdx.x;
  int b = i / 3, d = (i % 3) * 256 + threadIdx.x;
  float acc = 0.f;
  for (int p = 0; p < P_; ++p)
    acc += score[b * P_ + p] * Tout[((size_t)b * P_ + p) * D_ + d];
  tseg[b * D_ + d] = acc;
}

// ====================== QAB qa-half + A2 ======================
__global__ void qa_seg_k(const float* __restrict__ Tout, unsigned short* __restrict__ QAB,
                         const float* __restrict__ vseg, const float* __restrict__ tseg,
                         unsigned short* __restrict__ A2) {
  int blk = blockIdx.x;
  if (blk < 1728) {
    int idx = blk * 256 + threadIdx.x;
    int m = idx / 96, d8 = (idx % 96) * 8;
    int b = m / RPB_;
    const float* at = Tout + (size_t)(RP_ + m) * D_ + d8;
    const float* qq = Tout + (size_t)(RP_ + RA_ + b) * D_ + d8;
    uint4 p;
    p.x = pk2(at[0] + qq[0], at[1] + qq[1]);
    p.y = pk2(at[2] + qq[2], at[3] + qq[3]);
    p.z = pk2(at[4] + qq[4], at[5] + qq[5]);
    p.w = pk2(at[6] + qq[6], at[7] + qq[7]);
    *(uint4*)(QAB + (size_t)m * 1536 + d8) = p;
  } else {
    int idx = (blk - 1728) * 256 + threadIdx.x;
    int b = idx / 192, seg = (idx % 192) * 8;
    const float* src = (seg < D_) ? (vseg + b * D_ + seg) : (tseg + b * D_ + seg - D_);
    float4 a = *(const float4*)src;
    float4 c = *(const float4*)(src + 4);
    uint4 p; p.x = pk2(a.x, a.y); p.y = pk2(a.z, a.w); p.z = pk2(c.x, c.y); p.w = pk2(c.z, c.w);
    *(uint4*)(A2 + (size_t)b * 1536 + seg) = p;
  }
}

// ====================== gather H + logits init ======================
__global__ void gatherz_k(const unsigned short* __restrict__ xall, const int* __restrict__ label,
                          const float* __restrict__ state0, unsigned short* __restrict__ H,
                          const float* __restrict__ bq2, float* __restrict__ logits) {
  int idx = blockIdx.x * 256 + threadIdx.x;
  if (idx < RA_) logits[idx] = bq2[0];
  int m = idx / 96, d8 = (idx % 96) * 8;
  int b = m / S_, s = m % S_;
  if (s == 0) {
    float4 a = *(const float4*)(state0 + d8);
    float4 c = *(const float4*)(state0 + d8 + 4);
    uint4 p; p.x = pk2(a.x, a.y); p.y = pk2(a.z, a.w); p.z = pk2(c.x, c.y); p.w = pk2(c.z, c.w);
    *(uint4*)(H + (size_t)m * D_ + d8) = p;
  } else {
    int lab = label[b * S_ + (s - 1)];
    const unsigned short* src = xall + (((size_t)b * S_ + (s - 1)) * A_ + lab) * D_ + d8;
    *(uint4*)(H + (size_t)m * D_ + d8) = *(const uint4*)src;
  }
}

__global__ void gru_gates_k(const unsigned short* __restrict__ gi, const unsigned short* __restrict__ gh,
                            const unsigned short* __restrict__ H, unsigned short* __restrict__ hnew) {
  int idx = blockIdx.x * 256 + threadIdx.x;
  int m = idx / 96, d8 = (idx % 96) * 8;
  int bs = m / A_;
  const unsigned short* gim = gi + (size_t)m * G3_;
  const unsigned short* ghm = gh + (size_t)bs * G3_;
  s16x8 ir8 = *(const s16x8*)(gim + d8);
  s16x8 iz8 = *(const s16x8*)(gim + D_ + d8);
  s16x8 in8 = *(const s16x8*)(gim + 2 * D_ + d8);
  s16x8 hr8 = *(const s16x8*)(ghm + d8);
  s16x8 hz8 = *(const s16x8*)(ghm + D_ + d8);
  s16x8 hn8 = *(const s16x8*)(ghm + 2 * D_ + d8);
  s16x8 h8  = *(const s16x8*)(H + (size_t)bs * D_ + d8);
  s16x8 o;
#pragma unroll
  for (int j = 0; j < 8; ++j) {
    float r = 1.f / (1.f + __expf(-(bf2f((unsigned short)ir8[j]) + bf2f((unsigned short)hr8[j]))));
    float z = 1.f / (1.f + __expf(-(bf2f((unsigned short)iz8[j]) + bf2f((unsigned short)hz8[j]))));
    float n = tanhf(bf2f((unsigned short)in8[j]) + r * bf2f((unsigned short)hn8[j]));
    float h = bf2f((unsigned short)h8[j]);
    o[j] = (short)f2bf((1.f - z) * n + z * h);
  }
  *(s16x8*)(hnew + (size_t)m * D_ + d8) = o;
}

__global__ void loss_k(const float* __restrict__ logits, const int* __restrict__ label,
                       float* __restrict__ out) {
  __shared__ float red[256];
  int tid = threadIdx.x;
  float ls = 0.f;
  if (tid < RH_) {
    const float* lg = logits + (size_t)tid * A_;
    float mx = -INFINITY;
    for (int a = 0; a < A_; ++a) mx = fmaxf(mx, lg[a]);
    float sum = 0.f;
    for (int a = 0; a < A_; ++a) sum += __expf(lg[a] - mx);
    ls = (logf(sum) + mx) - lg[label[tid]];
  }
  red[tid] = ls;
  for (int o = 128; o > 0; o >>= 1) {
    __syncthreads();
    if (tid < o) red[tid] += red[tid + o];
  }
  if (tid == 0) out[0] = red[0] / (float)RH_;
}

extern "C" void kernel_launch(void* const* d_in, const int* in_sizes, int n_in,
                              void* d_out, int out_size, void* d_ws, size_t ws_size,
                              hipStream_t stream) {
  (void)in_sizes; (void)n_in; (void)out_size; (void)ws_size;
  const float* video      = (const float*)d_in[0];
  const float* para       = (const float*)d_in[1];
  const float* question   = (const float*)d_in[2];
  const float* a_texts    = (const float*)d_in[3];
  const float* a_buttons  = (const float*)d_in[4];
  const float* paras_score= (const float*)d_in[5];
  const int*   starts     = (const int*)d_in[6];
  const int*   ends       = (const int*)d_in[7];
  const int*   label      = (const int*)d_in[8];
  const float* wv1 = (const float*)d_in[9];  const float* bv1 = (const float*)d_in[10];
  const float* wv2 = (const float*)d_in[11]; const float* bv2 = (const float*)d_in[12];
  const float* wt1 = (const float*)d_in[13]; const float* bt1 = (const float*)d_in[14];
  const float* wt2 = (const float*)d_in[15]; const float* bt2 = (const float*)d_in[16];
  const float* wp1 = (const float*)d_in[17]; const float* bp1 = (const float*)d_in[18];
  const float* wp2 = (const float*)d_in[19]; const float* bp2 = (const float*)d_in[20];
  const float* w_ih= (const float*)d_in[21]; const float* b_ih= (const float*)d_in[22];
  const float* w_hh= (const float*)d_in[23]; const float* b_hh= (const float*)d_in[24];
  const float* wq1 = (const float*)d_in[25]; const float* bq1 = (const float*)d_in[26];
  const float* wq2 = (const float*)d_in[27]; const float* bq2 = (const float*)d_in[28];
  const float* state0 = (const float*)d_in[29];

  char* base = (char*)d_ws;
  unsigned short* wt1t = (unsigned short*)(base + 0);
  unsigned short* wt2t = (unsigned short*)(base + 1179648);
  unsigned short* wv1t = (unsigned short*)(base + 2359296);
  unsigned short* wv2t = (unsigned short*)(base + 3538944);
  unsigned short* wq1t = (unsigned short*)(base + 4718592);
  unsigned short* wp1tt= (unsigned short*)(base + 5898240);
  unsigned short* wp1bt= (unsigned short*)(base + 15335424);
  unsigned short* wp2t = (unsigned short*)(base + 24772608);
  unsigned short* wiht = (unsigned short*)(base + 29491200);
  unsigned short* whht = (unsigned short*)(base + 33030144);
  unsigned short* Acat = (unsigned short*)(base + 36569088);   // [26384,768]
  unsigned short* Hid  = (unsigned short*)(base + 77094912);   // [26384,768] -> hidp -> gib
  unsigned short* hidp = Hid;
  unsigned short* gib  = Hid;
  float*          Tout = (float*)(base + 117620736);           // [5392,768] f32
  unsigned short* QAB  = (unsigned short*)(base + 134184960);  // [4608,1536] -> hnew
  unsigned short* hnew = QAB;
  unsigned short* xall = (unsigned short*)(base + 148340736);  // [4608,768]
  unsigned short* Hbf  = (unsigned short*)(base + 155418624);  // [192,768]
  unsigned short* ghb  = (unsigned short*)(base + 155713536);  // [192,2304]
  char* sm = base + 156598272;
  float* wseg   = (float*)(sm + 0);
  float* score  = (float*)(sm + 65536);
  float* tseg   = (float*)(sm + 68608);
  float* vseg   = (float*)(sm + 117760);
  unsigned short* A2 = (unsigned short*)(sm + 166912);
  float* baseb  = (float*)(sm + 216064);
  float* logits = (float*)(sm + 412672);

  dim3 blk(256), blk5(512);
  TPtrs tp;
  tp.s[0] = wt1; tp.d[0] = wt1t;
  tp.s[1] = wt2; tp.d[1] = wt2t;
  tp.s[2] = wv1; tp.d[2] = wv1t;
  tp.s[3] = wv2; tp.d[3] = wv2t;
  tp.s[4] = wq1; tp.d[4] = wq1t;
  tp.s[5] = wp1;              tp.d[5] = wp1tt;
  tp.s[6] = wp1 + 1536 * D4_; tp.d[6] = wp1bt;
  tp.s[7] = wp2; tp.d[7] = wp2t;
  tp.s[8] = w_ih; tp.d[8] = wiht;
  tp.s[9] = w_hh; tp.d[9] = whht;

  // 1. transposes + softmax
  transpose_all_k<<<17857, blk, 0, stream>>>(tp, paras_score, score);
  // 2. pack all inputs into Acat + segment weights + zero vseg
  pack_segw_k<<<9958, blk, 0, stream>>>(video, a_buttons, para, a_texts, question,
                                        Acat, score, starts, ends, wseg, vseg);
  // 3. unified MLP layer 1 (26384 rows; rows<20992 use wv1 else wt1)  [r3-proven 256 structure]
  gemm256m<1,0,0><<<dim3(3, 104), blk5, 0, stream>>>(
      Acat, wv1t, bv1, wt1t, bt1, 20992, Hid, D_,
      nullptr, nullptr, nullptr, nullptr, 26384, D_, D_);
  // 4. unified MLP layer 2 (video -> atomic vseg; ab -> QAB; para/at/q -> Tout f32)
  gemm256m<0,2,0><<<dim3(3, 104), blk5, 0, stream>>>(
      Hid, wv2t, bv2, wt2t, bt2, 20992, nullptr, 0,
      wseg, vseg, QAB, Tout, 26384, D_, D_);
  // 5. tseg
  tseg_k<<<48, blk, 0, stream>>>(Tout, score, tseg);
  // 6. QAB qa-half + A2
  qa_seg_k<<<1740, blk, 0, stream>>>(Tout, QAB, vseg, tseg, A2);
  // 7. baseb = A2 @ wp1_top + bp1
  gemmdb_f32<<<dim3(24, 1), blk, 0, stream>>>(A2, wp1tt, bp1, baseb, D4_, B_, D4_, 1536);
  // 8. hidp = relu(QAB @ wp1_bot + baseb[b])  [r3-proven: 78us]
  gemm256m<1,0,1><<<dim3(12, 18), blk5, 0, stream>>>(
      QAB, wp1bt, baseb, wp1bt, baseb, 1 << 30, hidp, D4_,
      nullptr, nullptr, nullptr, nullptr, RA_, D4_, 1536);
  // 9. xall = hidp @ wp2 + bp2
  gemmph<0,0><<<dim3(6, 36), blk, 0, stream>>>(
      hidp, wp2t, bp2, wp2t, bp2, 1 << 30, xall, D_, nullptr, 0, 0,
      nullptr, nullptr, RA_, D_, D4_);
  // 10. gather H + logits init
  gatherz_k<<<72, blk, 0, stream>>>(xall, label, state0, Hbf, bq2, logits);
  // 11. gi+gh merged: rows<4608 use w_ih -> gib, else w_hh -> ghb
  gemmph<0,0><<<dim3(18, 38), blk, 0, stream>>>(
      xall, wiht, b_ih, whht, b_hh, 4608, gib, G3_, ghb, G3_, 4608,
      nullptr, nullptr, 4800, G3_, D_);
  // 12. gates -> hnew
  gru_gates_k<<<1728, blk, 0, stream>>>(gib, ghb, Hbf, hnew);
  // 13. wq1 GEMM with fused logits
  gemmph<1,3><<<dim3(6, 36), blk, 0, stream>>>(
      hnew, wq1t, bq1, wq1t, bq1, 1 << 30, nullptr, 0, nullptr, 0, 0,
      wq2, logits, RA_, D_, D_);
  // 14. loss
  loss_k<<<1, blk, 0, stream>>>(logits, label, (float*)d_out);
}

// Round 13
// 685.891 us; speedup vs baseline: 1.0463x; 1.0463x over previous
//
#include <hip/hip_runtime.h>
#include <hip/hip_bf16.h>
#include <math.h>

#define B_ 16
#define T_ 1024
#define P_ 48
#define S_ 12
#define A_ 24
#define D_ 768
#define D4_ 3072
#define G3_ 2304
#define RV_ (B_*T_)      // 16384
#define RP_ (B_*P_)      // 768
#define RA_ (B_*S_*A_)   // 4608
#define RH_ (B_*S_)      // 192
#define RPB_ 288

typedef float f32x4 __attribute__((ext_vector_type(4)));
typedef short s16x8 __attribute__((ext_vector_type(8)));

__device__ __forceinline__ unsigned short f2bf(float f) {
  unsigned int u = __float_as_uint(f);
  u += 0x7FFF + ((u >> 16) & 1);
  return (unsigned short)(u >> 16);
}
__device__ __forceinline__ unsigned int pk2(float lo, float hi) {
  return (unsigned int)f2bf(lo) | ((unsigned int)f2bf(hi) << 16);
}
__device__ __forceinline__ float bf2f(unsigned short u) {
  return __uint_as_float(((unsigned int)u) << 16);
}
__device__ __forceinline__ void gload16(const void* g, void* l) {
  __builtin_amdgcn_global_load_lds((const __attribute__((address_space(1))) void*)g,
                                   (__attribute__((address_space(3))) void*)l, 16, 0, 0);
}
__device__ __forceinline__ int xcd_swizzle(int orig, int nwg) {
  int q = nwg >> 3, r = nwg & 7;
  int xcd = orig & 7, local = orig >> 3;
  return (xcd < r ? xcd * (q + 1) : r * (q + 1) + (xcd - r) * q) + local;
}

#define VMW8 asm volatile("s_waitcnt vmcnt(8)" ::: "memory")
#define VMW4 asm volatile("s_waitcnt vmcnt(4)" ::: "memory")
#define VMW0 asm volatile("s_waitcnt vmcnt(0)" ::: "memory")

// ====================== gemmph: counted-vmcnt phased GEMM (steps 3/4/9/11/13) ======================
// C = act(A[M,K] @ W[N,K]^T + bias); W/bias selected per row-block (row<wsplit -> 0).
// MODE: 0 = bf16 out (optional row-split C0/C1 at osplit)
//       2 = mlp-L2 routing: rows<16384 atomic wseg-weighted into vseg;
//           <20992 bf16 -> QAB col+768; else f32 -> Tout(row-20992)
//       3 = fused logits: atomicAdd(logits[row], sum_col relu(v)*wq2[col])
template<int BM, int BN, int TH, int ACT, int MODE, int B2D>
__global__ __launch_bounds__(TH, 2)
void gemmph(const unsigned short* __restrict__ A,
            const unsigned short* __restrict__ Wt0, const float* __restrict__ bias0,
            const unsigned short* __restrict__ Wt1, const float* __restrict__ bias1,
            int wsplit,
            void* __restrict__ C0, int ldc0,
            void* __restrict__ C1, int ldc1, int osplit,
            const float* __restrict__ xv0,   // MODE3: wq2 | MODE2: wseg
            float* __restrict__ xv1,         // MODE3: logits | MODE2: vseg
            unsigned short* __restrict__ xq, // MODE2: QAB
            float* __restrict__ xt,          // MODE2: Tout
            int M, int N, int K)
{
  constexpr int MRF = BM / 32;
  __shared__ __align__(16) unsigned short As[2][2][BM][32];
  __shared__ __align__(16) unsigned short Bs[2][2][BN][32];
  const int tid  = threadIdx.x;
  const int lane = tid & 63;
  const int wid  = tid >> 6;
  const int wm = (BM == 256) ? (wid >> 2) * 128 : (wid >> 1) * 64;
  const int wn = (BM == 256) ? (wid & 3) * 64   : (wid & 1) * 64;
  const int gx = gridDim.x;
  int swz = xcd_swizzle(blockIdx.y * gx + blockIdx.x, gx * gridDim.y);
  const int bm0 = (swz / gx) * BM, bn0 = (swz % gx) * BN;

  const unsigned short* W = (bm0 < wsplit) ? Wt0 : Wt1;
  const float* bias = (bm0 < wsplit) ? bias0 : bias1;

  const int srow = (wid * 2) * 16 + (lane >> 2);
  const int sslot = lane & 3;

  f32x4 acc[MRF][4] = {};
  const int fr = lane & 15, fq = lane >> 4;
  const int sws = (fq ^ (fr & 3)) * 8;

  auto stage = [&](int buf, int ks, int kt) {
#pragma unroll
    for (int c = 0; c < 2; ++c) {
      int r = srow + c * 16;
      int ksl = sslot ^ (r & 3);
      int ar = bm0 + r; if (ar > M - 1) ar = M - 1;
      gload16(A + (size_t)ar * K + kt * 64 + ks * 32 + ksl * 8, &As[buf][ks][(wid * 2 + c) * 16][0]);
      gload16(W + (size_t)(bn0 + r) * K + kt * 64 + ks * 32 + ksl * 8, &Bs[buf][ks][(wid * 2 + c) * 16][0]);
    }
  };

  auto compute = [&](int cb, int ks) {
    s16x8 af[MRF], bf4[4];
#pragma unroll
    for (int i = 0; i < MRF; ++i)
      af[i] = *(const s16x8*)(&As[cb][ks][wm + i * 16 + fr][sws]);
#pragma unroll
    for (int i = 0; i < 4; ++i)
      bf4[i] = *(const s16x8*)(&Bs[cb][ks][wn + i * 16 + fr][sws]);
    __builtin_amdgcn_s_setprio(1);
#pragma unroll
    for (int mi = 0; mi < MRF; ++mi)
#pragma unroll
      for (int ni = 0; ni < 4; ++ni)
        acc[mi][ni] = __builtin_amdgcn_mfma_f32_16x16x32_bf16(af[mi], bf4[ni], acc[mi][ni], 0, 0, 0);
    __builtin_amdgcn_s_setprio(0);
  };

  const int nt = K >> 6;
  stage(0, 0, 0); stage(0, 1, 0); stage(1, 0, 1);
  for (int t = 0; t < nt; ++t) {
    const int cb = t & 1;
    if (t + 1 < nt) { VMW8; __builtin_amdgcn_s_barrier(); stage(cb ^ 1, 1, t + 1); }
    else            { VMW4; __builtin_amdgcn_s_barrier(); }
    compute(cb, 0);
    if (t + 2 < nt)       { VMW8; __builtin_amdgcn_s_barrier(); stage(cb, 0, t + 2); }
    else if (t + 2 == nt) { VMW8; __builtin_amdgcn_s_barrier(); }
    else                  { VMW0; __builtin_amdgcn_s_barrier(); }
    compute(cb, 1);
  }

  // ---------------- epilogue ----------------
  if (MODE == 3) {
#pragma unroll
    for (int mi = 0; mi < MRF; ++mi)
#pragma unroll
      for (int r = 0; r < 4; ++r) {
        int row = bm0 + wm + mi * 16 + fq * 4 + r;
        float part = 0.f;
#pragma unroll
        for (int ni = 0; ni < 4; ++ni) {
          int col = bn0 + wn + ni * 16 + fr;
          float v = fmaxf(acc[mi][ni][r] + bias[col], 0.f);
          part += v * xv0[col];
        }
        part += __shfl_xor(part, 1);
        part += __shfl_xor(part, 2);
        part += __shfl_xor(part, 4);
        part += __shfl_xor(part, 8);
        if (fr == 0 && row < M) atomicAdd(&xv1[row], part);
      }
  } else if (MODE == 2 && bm0 < 16384) {
    // video rows: vseg[b,col] += sum_rows wseg[row]*v  (video_v never stored)
    float s[4] = {0.f, 0.f, 0.f, 0.f};
#pragma unroll
    for (int mi = 0; mi < MRF; ++mi)
#pragma unroll
      for (int r = 0; r < 4; ++r) {
        int row = bm0 + wm + mi * 16 + fq * 4 + r;
        float wv = xv0[row];
#pragma unroll
        for (int ni = 0; ni < 4; ++ni) {
          int col = bn0 + wn + ni * 16 + fr;
          s[ni] += wv * (acc[mi][ni][r] + bias[col]);
        }
      }
    int b = bm0 >> 10;
#pragma unroll
    for (int ni = 0; ni < 4; ++ni) {
      s[ni] += __shfl_xor(s[ni], 16);
      s[ni] += __shfl_xor(s[ni], 32);
      if (fq == 0) atomicAdd(&xv1[b * D_ + bn0 + wn + ni * 16 + fr], s[ni]);
    }
  } else {
#pragma unroll
    for (int ni = 0; ni < 4; ++ni) {
      int col = bn0 + wn + ni * 16 + fr;
      float bb = B2D ? 0.f : bias[col];
#pragma unroll
      for (int mi = 0; mi < MRF; ++mi)
#pragma unroll
        for (int r = 0; r < 4; ++r) {
          int row = bm0 + wm + mi * 16 + fq * 4 + r;
          if (row >= M) continue;
          float v = acc[mi][ni][r] + (B2D ? bias[(size_t)(row / RPB_) * N + col] : bb);
          if (ACT) v = fmaxf(v, 0.f);
          if (MODE == 2) {
            if (row < 20992) xq[(size_t)(row - 16384) * 1536 + D_ + col] = f2bf(v);
            else             xt[(size_t)(row - 20992) * D_ + col] = v;
          } else {
            if (osplit && row >= osplit) ((unsigned short*)C1)[(size_t)(row - osplit) * ldc1 + col] = f2bf(v);
            else ((unsigned short*)C0)[(size_t)row * ldc0 + col] = f2bf(v);
          }
        }
    }
  }
}

// ============ gemm256m: r3-proven 256x256 BK=64 dbuf GEMM — step 8 only (216 blocks, K=1536) ============
template<int ACT, int B2D>
__global__ __launch_bounds__(512, 2)
void gemm256m(const unsigned short* __restrict__ A,
              const unsigned short* __restrict__ Wt,
              const float* __restrict__ bias,
              unsigned short* __restrict__ C0, int ldc0,
              int M, int N, int K)
{
  __shared__ __align__(16) unsigned short As[2][16384];
  __shared__ __align__(16) unsigned short Bs[2][16384];
  const int tid  = threadIdx.x;
  const int lane = tid & 63;
  const int wid  = tid >> 6;
  const int wm = (wid >> 2) * 128;
  const int wn = (wid & 3) * 64;
  const int gx = gridDim.x;
  int swz = xcd_swizzle(blockIdx.y * gx + blockIdx.x, gx * gridDim.y);
  const int bm0 = (swz / gx) * 256, bn0 = (swz % gx) * 256;

  const int srow = wid * 32 + (lane >> 3);
  const int skk  = (lane & 7) * 8;
  const unsigned short* gA[4];
  const unsigned short* gB[4];
#pragma unroll
  for (int c = 0; c < 4; ++c) {
    int r = bm0 + srow + c * 8; if (r > M - 1) r = M - 1;
    gA[c] = A  + (size_t)r * K + skk;
    gB[c] = Wt + (size_t)(bn0 + srow + c * 8) * K + skk;
  }

  f32x4 acc[8][4] = {};
  const int fr = lane & 15, fq = lane >> 4;
  const int nt = K / 64;

#pragma unroll
  for (int c = 0; c < 4; ++c) {
    gload16(gA[c], &As[0][wid * 2048 + c * 512]);
    gload16(gB[c], &Bs[0][wid * 2048 + c * 512]);
  }
  __syncthreads();

  for (int t = 0; t < nt; ++t) {
    if (t + 1 < nt) {
      const int nb = (t + 1) & 1;
      const size_t ko = (size_t)(t + 1) * 64;
#pragma unroll
      for (int c = 0; c < 4; ++c) {
        gload16(gA[c] + ko, &As[nb][wid * 2048 + c * 512]);
        gload16(gB[c] + ko, &Bs[nb][wid * 2048 + c * 512]);
      }
    }
    const int cb = t & 1;
#pragma unroll
    for (int ks = 0; ks < 2; ++ks) {
      s16x8 af[8], bf4[4];
#pragma unroll
      for (int i = 0; i < 8; ++i)
        af[i] = *(const s16x8*)(&As[cb][(wm + i * 16 + fr) * 64 + ks * 32 + fq * 8]);
#pragma unroll
      for (int i = 0; i < 4; ++i)
        bf4[i] = *(const s16x8*)(&Bs[cb][(wn + i * 16 + fr) * 64 + ks * 32 + fq * 8]);
#pragma unroll
      for (int mi = 0; mi < 8; ++mi)
#pragma unroll
        for (int ni = 0; ni < 4; ++ni)
          acc[mi][ni] = __builtin_amdgcn_mfma_f32_16x16x32_bf16(af[mi], bf4[ni], acc[mi][ni], 0, 0, 0);
    }
    __syncthreads();
  }

#pragma unroll
  for (int ni = 0; ni < 4; ++ni) {
    int col = bn0 + wn + ni * 16 + fr;
    float bb = B2D ? 0.f : bias[col];
#pragma unroll
    for (int mi = 0; mi < 8; ++mi)
#pragma unroll
      for (int r = 0; r < 4; ++r) {
        int row = bm0 + wm + mi * 16 + fq * 4 + r;
        if (row >= M) continue;
        float v = acc[mi][ni][r] + (B2D ? bias[(size_t)(row / RPB_) * N + col] : bb);
        if (ACT) v = fmaxf(v, 0.f);
        C0[(size_t)row * ldc0 + col] = f2bf(v);
      }
  }
}

// ====================== gemmdb_f32 (tiny baseb GEMM) ======================
__global__ __launch_bounds__(256, 2)
void gemmdb_f32(const unsigned short* __restrict__ A,
                const unsigned short* __restrict__ Wt,
                const float* __restrict__ bias,
                float* __restrict__ C0, int ldc0,
                int M, int N, int K)
{
  __shared__ __align__(16) unsigned short As[2][8192];
  __shared__ __align__(16) unsigned short Bs[2][8192];
  const int tid  = threadIdx.x;
  const int lane = tid & 63;
  const int wid  = tid >> 6;
  const int wm = (wid >> 1) * 64, wn = (wid & 1) * 64;
  const int bm0 = blockIdx.y * 128, bn0 = blockIdx.x * 128;
  const int srow = wid * 32 + (lane >> 3);
  const int skk  = (lane & 7) * 8;
  const unsigned short* gA[4];
  const unsigned short* gB[4];
#pragma unroll
  for (int c = 0; c < 4; ++c) {
    int r = bm0 + srow + c * 8; if (r > M - 1) r = M - 1;
    gA[c] = A  + (size_t)r * K + skk;
    gB[c] = Wt + (size_t)(bn0 + srow + c * 8) * K + skk;
  }
  f32x4 acc[4][4] = {};
  const int fr = lane & 15, fq = lane >> 4;
  const int nt = K / 64;
#pragma unroll
  for (int c = 0; c < 4; ++c) {
    gload16(gA[c], &As[0][wid * 2048 + c * 512]);
    gload16(gB[c], &Bs[0][wid * 2048 + c * 512]);
  }
  __syncthreads();
  for (int t = 0; t < nt; ++t) {
    if (t + 1 < nt) {
      const int nb = (t + 1) & 1;
      const int ko = (t + 1) * 64;
#pragma unroll
      for (int c = 0; c < 4; ++c) {
        gload16(gA[c] + ko, &As[nb][wid * 2048 + c * 512]);
        gload16(gB[c] + ko, &Bs[nb][wid * 2048 + c * 512]);
      }
    }
    const int cb = t & 1;
#pragma unroll
    for (int ks = 0; ks < 2; ++ks) {
      s16x8 af[4], bf4[4];
#pragma unroll
      for (int i = 0; i < 4; ++i) {
        af[i]  = *(const s16x8*)(&As[cb][(wm + i * 16 + fr) * 64 + ks * 32 + fq * 8]);
        bf4[i] = *(const s16x8*)(&Bs[cb][(wn + i * 16 + fr) * 64 + ks * 32 + fq * 8]);
      }
#pragma unroll
      for (int mi = 0; mi < 4; ++mi)
#pragma unroll
        for (int ni = 0; ni < 4; ++ni)
          acc[mi][ni] = __builtin_amdgcn_mfma_f32_16x16x32_bf16(af[mi], bf4[ni], acc[mi][ni], 0, 0, 0);
    }
    __syncthreads();
  }
#pragma unroll
  for (int ni = 0; ni < 4; ++ni) {
    int col = bn0 + wn + ni * 16 + fr;
    float bb = bias[col];
#pragma unroll
    for (int mi = 0; mi < 4; ++mi)
#pragma unroll
      for (int r = 0; r < 4; ++r) {
        int row = bm0 + wm + mi * 16 + fq * 4 + r;
        if (row < M) C0[(size_t)row * ldc0 + col] = acc[mi][ni][r] + bb;
      }
  }
}

// ====================== transposes + softmax ======================
struct TPtrs { const float* s[10]; unsigned short* d[10]; };

__global__ void transpose_all_k(TPtrs p, const float* __restrict__ ps, float* __restrict__ score) {
  constexpr int KN[10][2] = {{768,768},{768,768},{768,768},{768,768},{768,768},
                             {1536,3072},{1536,3072},{3072,768},{768,2304},{768,2304}};
  constexpr int TC[10] = {576,576,576,576,576,4608,4608,2304,1728,1728};
  int bid = blockIdx.x;
  if (bid == 17856) {
    int lane = threadIdx.x & 63, g = threadIdx.x >> 6;
#pragma unroll
    for (int rep = 0; rep < 4; ++rep) {
      int b = rep * 4 + g;
      float v = (lane < P_) ? ps[b * P_ + lane] : -INFINITY;
      float m = v;
      for (int o = 32; o > 0; o >>= 1) m = fmaxf(m, __shfl_xor(m, o));
      float e = (lane < P_) ? __expf(v - m) : 0.f;
      float s = e;
      for (int o = 32; o > 0; o >>= 1) s += __shfl_xor(s, o);
      if (lane < P_) score[b * P_ + lane] = e / s;
    }
    return;
  }
  int j = 0, local = bid;
  while (local >= TC[j]) { local -= TC[j]; ++j; }
  const int K = KN[j][0], N = KN[j][1];
  const float* W = p.s[j];
  unsigned short* Wt = p.d[j];
  int tx = local % (N >> 5), ty = local / (N >> 5);
  __shared__ float t[32][33];
  int n0 = tx * 32, k0 = ty * 32;
  int c = threadIdx.x & 31, r8 = threadIdx.x >> 5;
#pragma unroll
  for (int i = 0; i < 4; ++i) {
    int r = r8 + i * 8;
    t[r][c] = W[(size_t)(k0 + r) * N + n0 + c];
  }
  __syncthreads();
#pragma unroll
  for (int i = 0; i < 4; ++i) {
    int r = r8 + i * 8;
    Wt[(size_t)(n0 + r) * K + k0 + c] = f2bf(t[c][r]);
  }
}

// ====================== pack inputs + segment weights + zero vseg ======================
__global__ void pack_segw_k(const float* __restrict__ video, const float* __restrict__ abut,
                            const float* __restrict__ para, const float* __restrict__ atex,
                            const float* __restrict__ quest,
                            unsigned short* __restrict__ Acat,
                            const float* __restrict__ score, const int* __restrict__ starts,
                            const int* __restrict__ ends, float* __restrict__ w,
                            float* __restrict__ vseg) {
  int blk = blockIdx.x;
  if (blk < 9894) {
    int idx = blk * 256 + threadIdx.x;
    int r = idx / 96, d8 = (idx % 96) * 8;
    const float* src;
    if (r < 16384)      src = video + (size_t)r * D_;
    else if (r < 20992) src = abut + (size_t)(r - 16384) * D_;
    else if (r < 21760) src = para + (size_t)(r - 20992) * D_;
    else if (r < 26368) src = atex + (size_t)(r - 21760) * D_;
    else                src = quest + (size_t)(r - 26368) * D_;
    float4 a = *(const float4*)(src + d8);
    float4 b = *(const float4*)(src + d8 + 4);
    uint4 pk; pk.x = pk2(a.x, a.y); pk.y = pk2(a.z, a.w); pk.z = pk2(b.x, b.y); pk.w = pk2(b.z, b.w);
    *(uint4*)(Acat + (size_t)r * D_ + d8) = pk;
  } else {
    int idx = (blk - 9894) * 256 + threadIdx.x;
    int b = idx >> 10, t = idx & 1023;
    float acc = 0.f;
    for (int p = 0; p < P_; ++p) {
      int s = starts[b * P_ + p], e = ends[b * P_ + p];
      float sc = score[b * P_ + p];
      if (s >= e) { if (t == s) acc += sc; }
      else if (t >= s && t < e) acc += sc / (float)(e - s);
    }
    w[idx] = acc;
    if (idx < B_ * D_) vseg[idx] = 0.f;
  }
}

// ====================== tseg reduction over Tout para rows ======================
__global__ void tseg_k(const float* __restrict__ Tout, const float* __restrict__ score,
                       float* __restrict__ tseg) {
  int i = blockIdx.x;
  int b = i / 3, d = (i % 3) * 256 + threadIdx.x;
  float acc = 0.f;
  for (int p = 0; p < P_; ++p)
    acc += score[b * P_ + p] * Tout[((size_t)b * P_ + p) * D_ + d];
  tseg[b * D_ + d] = acc;
}

// ====================== QAB qa-half + A2 ======================
__global__ void qa_seg_k(const float* __restrict__ Tout, unsigned short* __restrict__ QAB,
                         const float* __restrict__ vseg, const float* __restrict__ tseg,
                         unsigned short* __restrict__ A2) {
  int blk = blockIdx.x;
  if (blk < 1728) {
    int idx = blk * 256 + threadIdx.x;
    int m = idx / 96, d8 = (idx % 96) * 8;
    int b = m / RPB_;
    const float* at = Tout + (size_t)(RP_ + m) * D_ + d8;
    const float* qq = Tout + (size_t)(RP_ + RA_ + b) * D_ + d8;
    uint4 p;
    p.x = pk2(at[0] + qq[0], at[1] + qq[1]);
    p.y = pk2(at[2] + qq[2], at[3] + qq[3]);
    p.z = pk2(at[4] + qq[4], at[5] + qq[5]);
    p.w = pk2(at[6] + qq[6], at[7] + qq[7]);
    *(uint4*)(QAB + (size_t)m * 1536 + d8) = p;
  } else {
    int idx = (blk - 1728) * 256 + threadIdx.x;
    int b = idx / 192, seg = (idx % 192) * 8;
    const float* src = (seg < D_) ? (vseg + b * D_ + seg) : (tseg + b * D_ + seg - D_);
    float4 a = *(const float4*)src;
    float4 c = *(const float4*)(src + 4);
    uint4 p; p.x = pk2(a.x, a.y); p.y = pk2(a.z, a.w); p.z = pk2(c.x, c.y); p.w = pk2(c.z, c.w);
    *(uint4*)(A2 + (size_t)b * 1536 + seg) = p;
  }
}

// ====================== gather H + logits init ======================
__global__ void gatherz_k(const unsigned short* __restrict__ xall, const int* __restrict__ label,
                          const float* __restrict__ state0, unsigned short* __restrict__ H,
                          const float* __restrict__ bq2, float* __restrict__ logits) {
  int idx = blockIdx.x * 256 + threadIdx.x;
  if (idx < RA_) logits[idx] = bq2[0];
  int m = idx / 96, d8 = (idx % 96) * 8;
  int b = m / S_, s = m % S_;
  if (s == 0) {
    float4 a = *(const float4*)(state0 + d8);
    float4 c = *(const float4*)(state0 + d8 + 4);
    uint4 p; p.x = pk2(a.x, a.y); p.y = pk2(a.z, a.w); p.z = pk2(c.x, c.y); p.w = pk2(c.z, c.w);
    *(uint4*)(H + (size_t)m * D_ + d8) = p;
  } else {
    int lab = label[b * S_ + (s - 1)];
    const unsigned short* src = xall + (((size_t)b * S_ + (s - 1)) * A_ + lab) * D_ + d8;
    *(uint4*)(H + (size_t)m * D_ + d8) = *(const uint4*)src;
  }
}

__global__ void gru_gates_k(const unsigned short* __restrict__ gi, const unsigned short* __restrict__ gh,
                            const unsigned short* __restrict__ H, unsigned short* __restrict__ hnew) {
  int idx = blockIdx.x * 256 + threadIdx.x;
  int m = idx / 96, d8 = (idx % 96) * 8;
  int bs = m / A_;
  const unsigned short* gim = gi + (size_t)m * G3_;
  const unsigned short* ghm = gh + (size_t)bs * G3_;
  s16x8 ir8 = *(const s16x8*)(gim + d8);
  s16x8 iz8 = *(const s16x8*)(gim + D_ + d8);
  s16x8 in8 = *(const s16x8*)(gim + 2 * D_ + d8);
  s16x8 hr8 = *(const s16x8*)(ghm + d8);
  s16x8 hz8 = *(const s16x8*)(ghm + D_ + d8);
  s16x8 hn8 = *(const s16x8*)(ghm + 2 * D_ + d8);
  s16x8 h8  = *(const s16x8*)(H + (size_t)bs * D_ + d8);
  s16x8 o;
#pragma unroll
  for (int j = 0; j < 8; ++j) {
    float r = 1.f / (1.f + __expf(-(bf2f((unsigned short)ir8[j]) + bf2f((unsigned short)hr8[j]))));
    float z = 1.f / (1.f + __expf(-(bf2f((unsigned short)iz8[j]) + bf2f((unsigned short)hz8[j]))));
    float n = tanhf(bf2f((unsigned short)in8[j]) + r * bf2f((unsigned short)hn8[j]));
    float h = bf2f((unsigned short)h8[j]);
    o[j] = (short)f2bf((1.f - z) * n + z * h);
  }
  *(s16x8*)(hnew + (size_t)m * D_ + d8) = o;
}

__global__ void loss_k(const float* __restrict__ logits, const int* __restrict__ label,
                       float* __restrict__ out) {
  __shared__ float red[256];
  int tid = threadIdx.x;
  float ls = 0.f;
  if (tid < RH_) {
    const float* lg = logits + (size_t)tid * A_;
    float mx = -INFINITY;
    for (int a = 0; a < A_; ++a) mx = fmaxf(mx, lg[a]);
    float sum = 0.f;
    for (int a = 0; a < A_; ++a) sum += __expf(lg[a] - mx);
    ls = (logf(sum) + mx) - lg[label[tid]];
  }
  red[tid] = ls;
  for (int o = 128; o > 0; o >>= 1) {
    __syncthreads();
    if (tid < o) red[tid] += red[tid + o];
  }
  if (tid == 0) out[0] = red[0] / (float)RH_;
}

extern "C" void kernel_launch(void* const* d_in, const int* in_sizes, int n_in,
                              void* d_out, int out_size, void* d_ws, size_t ws_size,
                              hipStream_t stream) {
  (void)in_sizes; (void)n_in; (void)out_size; (void)ws_size;
  const float* video      = (const float*)d_in[0];
  const float* para       = (const float*)d_in[1];
  const float* question   = (const float*)d_in[2];
  const float* a_texts    = (const float*)d_in[3];
  const float* a_buttons  = (const float*)d_in[4];
  const float* paras_score= (const float*)d_in[5];
  const int*   starts     = (const int*)d_in[6];
  const int*   ends       = (const int*)d_in[7];
  const int*   label      = (const int*)d_in[8];
  const float* wv1 = (const float*)d_in[9];  const float* bv1 = (const float*)d_in[10];
  const float* wv2 = (const float*)d_in[11]; const float* bv2 = (const float*)d_in[12];
  const float* wt1 = (const float*)d_in[13]; const float* bt1 = (const float*)d_in[14];
  const float* wt2 = (const float*)d_in[15]; const float* bt2 = (const float*)d_in[16];
  const float* wp1 = (const float*)d_in[17]; const float* bp1 = (const float*)d_in[18];
  const float* wp2 = (const float*)d_in[19]; const float* bp2 = (const float*)d_in[20];
  const float* w_ih= (const float*)d_in[21]; const float* b_ih= (const float*)d_in[22];
  const float* w_hh= (const float*)d_in[23]; const float* b_hh= (const float*)d_in[24];
  const float* wq1 = (const float*)d_in[25]; const float* bq1 = (const float*)d_in[26];
  const float* wq2 = (const float*)d_in[27]; const float* bq2 = (const float*)d_in[28];
  const float* state0 = (const float*)d_in[29];

  char* base = (char*)d_ws;
  unsigned short* wt1t = (unsigned short*)(base + 0);
  unsigned short* wt2t = (unsigned short*)(base + 1179648);
  unsigned short* wv1t = (unsigned short*)(base + 2359296);
  unsigned short* wv2t = (unsigned short*)(base + 3538944);
  unsigned short* wq1t = (unsigned short*)(base + 4718592);
  unsigned short* wp1tt= (unsigned short*)(base + 5898240);
  unsigned short* wp1bt= (unsigned short*)(base + 15335424);
  unsigned short* wp2t = (unsigned short*)(base + 24772608);
  unsigned short* wiht = (unsigned short*)(base + 29491200);
  unsigned short* whht = (unsigned short*)(base + 33030144);
  unsigned short* Acat = (unsigned short*)(base + 36569088);   // [26384,768]
  unsigned short* Hid  = (unsigned short*)(base + 77094912);   // [26384,768] -> hidp -> gib
  unsigned short* hidp = Hid;
  unsigned short* gib  = Hid;
  float*          Tout = (float*)(base + 117620736);           // [5392,768] f32
  unsigned short* QAB  = (unsigned short*)(base + 134184960);  // [4608,1536] -> hnew
  unsigned short* hnew = QAB;
  unsigned short* xall = (unsigned short*)(base + 148340736);  // [4608,768]
  unsigned short* Hbf  = (unsigned short*)(base + 155418624);  // [192,768]
  unsigned short* ghb  = (unsigned short*)(base + 155713536);  // [192,2304]
  char* sm = base + 156598272;
  float* wseg   = (float*)(sm + 0);
  float* score  = (float*)(sm + 65536);
  float* tseg   = (float*)(sm + 68608);
  float* vseg   = (float*)(sm + 117760);
  unsigned short* A2 = (unsigned short*)(sm + 166912);
  float* baseb  = (float*)(sm + 216064);
  float* logits = (float*)(sm + 412672);

  dim3 blk(256), blk5(512);
  TPtrs tp;
  tp.s[0] = wt1; tp.d[0] = wt1t;
  tp.s[1] = wt2; tp.d[1] = wt2t;
  tp.s[2] = wv1; tp.d[2] = wv1t;
  tp.s[3] = wv2; tp.d[3] = wv2t;
  tp.s[4] = wq1; tp.d[4] = wq1t;
  tp.s[5] = wp1;              tp.d[5] = wp1tt;
  tp.s[6] = wp1 + 1536 * D4_; tp.d[6] = wp1bt;
  tp.s[7] = wp2; tp.d[7] = wp2t;
  tp.s[8] = w_ih; tp.d[8] = wiht;
  tp.s[9] = w_hh; tp.d[9] = whht;

  // 1. transposes + softmax
  transpose_all_k<<<17857, blk, 0, stream>>>(tp, paras_score, score);
  // 2. pack all inputs into Acat + segment weights + zero vseg
  pack_segw_k<<<9958, blk, 0, stream>>>(video, a_buttons, para, a_texts, question,
                                        Acat, score, starts, ends, wseg, vseg);
  // 3. unified MLP layer 1 (26384 rows; rows<20992 use wv1 else wt1)  [r9: gemmph128, 1242 blocks]
  gemmph<128,128,256,1,0,0><<<dim3(6, 207), blk, 0, stream>>>(
      Acat, wv1t, bv1, wt1t, bt1, 20992, Hid, D_, nullptr, 0, 0,
      nullptr, nullptr, nullptr, nullptr, 26384, D_, D_);
  // 4. unified MLP layer 2 (video rows -> atomic vseg; ab -> QAB; para/at/q -> Tout f32)
  gemmph<128,128,256,0,2,0><<<dim3(6, 207), blk, 0, stream>>>(
      Hid, wv2t, bv2, wt2t, bt2, 20992, nullptr, 0, nullptr, 0, 0,
      wseg, vseg, QAB, Tout, 26384, D_, D_);
  // 5. tseg
  tseg_k<<<48, blk, 0, stream>>>(Tout, score, tseg);
  // 6. QAB qa-half + A2
  qa_seg_k<<<1740, blk, 0, stream>>>(Tout, QAB, vseg, tseg, A2);
  // 7. baseb = A2 @ wp1_top + bp1
  gemmdb_f32<<<dim3(24, 1), blk, 0, stream>>>(A2, wp1tt, bp1, baseb, D4_, B_, D4_, 1536);
  // 8. hidp = relu(QAB @ wp1_bot + baseb[b])  [r12: gemm256m, 216 blocks = single wave]
  gemm256m<1,1><<<dim3(12, 18), blk5, 0, stream>>>(
      QAB, wp1bt, baseb, hidp, D4_, RA_, D4_, 1536);
  // 9. xall = hidp @ wp2 + bp2
  gemmph<128,128,256,0,0,0><<<dim3(6, 36), blk, 0, stream>>>(
      hidp, wp2t, bp2, wp2t, bp2, 1 << 30, xall, D_, nullptr, 0, 0,
      nullptr, nullptr, nullptr, nullptr, RA_, D_, D4_);
  // 10. gather H + logits init
  gatherz_k<<<72, blk, 0, stream>>>(xall, label, state0, Hbf, bq2, logits);
  // 11. gi+gh merged: rows<4608 use w_ih -> gib, else w_hh -> ghb
  gemmph<128,128,256,0,0,0><<<dim3(18, 38), blk, 0, stream>>>(
      xall, wiht, b_ih, whht, b_hh, 4608, gib, G3_, ghb, G3_, 4608,
      nullptr, nullptr, nullptr, nullptr, 4800, G3_, D_);
  // 12. gates -> hnew
  gru_gates_k<<<1728, blk, 0, stream>>>(gib, ghb, Hbf, hnew);
  // 13. wq1 GEMM with fused logits
  gemmph<128,128,256,1,3,0><<<dim3(6, 36), blk, 0, stream>>>(
      hnew, wq1t, bq1, wq1t, bq1, 1 << 30, nullptr, 0, nullptr, 0, 0,
      wq2, logits, nullptr, nullptr, RA_, D_, D_);
  // 14. loss
  loss_k<<<1, blk, 0, stream>>>(logits, label, (float*)d_out);
}